// Round 11
// baseline (176.089 us; speedup 1.0000x reference)
//
#include <hip/hip_runtime.h>
#include <stdint.h>
#include <math.h>

#define T_STEPS 4096
#define BATCH   256
#define NSEG    1024     // 4-step cert segments per batch
#define EP      17       // [seg][*] cert pitch (16 ch + 1 pad)

// LIF step, threshold=1:  v'=alpha*v+xs; s=max(floor(v'),0); v=v'-s
__device__ __forceinline__ float lif_step(float& v, float xs, float alpha) {
    float vp = fmaf(alpha, v, xs);
    float fr = vp - floorf(vp);
    float vn = fminf(vp, fr);
    float s  = vp - vn;
    v = vn;
    return s;
}

__device__ __forceinline__ float ubf(uint32_t w, int k) {
    return (float)((w >> (k * 8)) & 0xffu);
}

// DPP helpers.  quad_perm xor1=0xB1, xor2=0x4E; row_shr:4=0x114, row_shr:8=
// 0x118 (within 16-lane DPP rows; bound_ctrl=true -> 0 for out-of-row src).
// R24 fix: dpp_ctrl MUST be an integer-constant expression -> template param
// (R23 failed to compile passing it as a runtime function argument).
template <int CTRL>
__device__ __forceinline__ float dppf(float v) {
    return __int_as_float(__builtin_amdgcn_mov_dpp(
        __float_as_int(v), CTRL, 0xF, 0xF, true));
}
__device__ __forceinline__ float qsum4(float v) {   // sum over 4-lane quad
    float r = v + dppf<0xB1>(v);
    return r + dppf<0x4E>(r);
}

// round-UP u16 quantization of cert maxima (sound: decode >= true value;
// 65535 decodes +huge -> always flags).  Range [-8, 8), quantum 2.44e-4.
__device__ __forceinline__ unsigned short encq(float m) {
    int q = (int)ceilf(fmaf(m, 4096.0f, 32768.0f));
    q = q < 0 ? 0 : (q > 65534 ? 65535 : q);
    return (unsigned short)q;
}
__device__ __forceinline__ float decq(uint32_t q) {
    return (q == 65535u) ? 1e30f : fmaf((float)q, 0.000244140625f, -8.0f);
}

__device__ __forceinline__ float dot16(const float wr[16],
    float4 c0, float4 c1, float4 c2, float4 c3)
{
    float p0 = fmaf(wr[1], c0.y, wr[0] * c0.x);
    p0 = fmaf(wr[2], c0.z, p0);  p0 = fmaf(wr[3], c0.w, p0);
    float p1 = fmaf(wr[5], c1.y, wr[4] * c1.x);
    p1 = fmaf(wr[6], c1.z, p1);  p1 = fmaf(wr[7], c1.w, p1);
    float p2 = fmaf(wr[9], c2.y, wr[8] * c2.x);
    p2 = fmaf(wr[10], c2.z, p2); p2 = fmaf(wr[11], c2.w, p2);
    float p3 = fmaf(wr[13], c3.y, wr[12] * c3.x);
    p3 = fmaf(wr[14], c3.z, p3); p3 = fmaf(wr[15], c3.w, p3);
    return (p0 + p1) + (p2 + p3);
}

// R23/R24: coalesced loads + in-register DPP compute, NO y materialization.
// Cross-round synthesis: R16's wall = 16x-amplified ds_read river (4096
// ds_read_b128/chunk x 12cy); R20/R22's wall = lane-private 256B reads (TA
// transaction inflation, ~1.8TB/s); R21 coalesced but paid select-chains +
// y-slab.  Here: lane = (chan-subset d=ln>>4, time-row rl=(ln>>2)&3, quad
// q=ln&3), channel c = 4d+q.  Per 16-row group: ONE coalesced wave load ->
// wave-private 1KB LDS stage (same-wave DS ordering, no barrier) -> per
// 4-row segment: 4x dot4 (weights in 16 VGPRs, loop-invariant), quad_perm
// sums complete 16-wide dots, then the 4-step LIF prefix scan runs in DPP:
//   z1 = y + a*shr4(y); z2 = z1 + a^2*shr8(z1)      (acc_j at row rl)
//   m0 = max-chain shr4/shr8 of z2; m1 = same of (z2 + a^(rl+1))
// bound_ctrl zero-fill = free segment boundary; writer lane rl=3 has exact
// m0/m1 (no zero contamination: shr8 pulls rl=1's pair-max).  Only certs
// {end f32, m0|m1 u16 round-up} go to LDS.  x read ONCE (no cg split).
// Composition (16ch x 8 eighths + 40-seg warmup), parallel repair, fused
// flag-gated tails: as proven in R20/R22.
__global__ __launch_bounds__(512) void fused(
    const float* __restrict__ x, const float* __restrict__ w1,
    const float* __restrict__ w2, const float* __restrict__ w3,
    float* __restrict__ out, uint8_t* __restrict__ s1t,
    uint8_t* __restrict__ s2t,
    float alpha, float one_m, float alpha4)
{
    const int tid = threadIdx.x;
    const int b   = blockIdx.x;
    const int wv  = tid >> 6;
    const int ln  = tid & 63;
    const int d   = ln >> 4;          // channel subset 0..3
    const int rl  = (ln >> 2) & 3;    // time-row within segment
    const int q   = ln & 3;           // x-quad / channel-within-subset
    const int c   = d * 4 + q;        // this lane's cert channel

    __shared__ float    endf[NSEG * EP];        // 68 KiB
    __shared__ uint32_t m01 [NSEG * EP];        // 68 KiB
    __shared__ float    xs  [8 * 256];          // 8 KiB wave-private stages
    __shared__ uint32_t sh_badseg[16][32];      // 2 KiB
    __shared__ uint8_t  sh_bm1[256];
    __shared__ uint8_t  sh_bm2[256];
    __shared__ int      sh_badch, sh_spike, sh_flag2;

    const float4* xq4 = (const float4*)(x + (size_t)b * T_STEPS * 16);

    if (tid < 64)        ((uint32_t*)sh_bm1)[tid] = 0u;
    else if (tid < 128)  ((uint32_t*)sh_bm2)[tid - 64] = 0u;
    else if (tid == 128) { sh_badch = 0; sh_spike = 0; sh_flag2 = 0; }

    // ---- weights: 4 float4/lane (channels 4d..4d+3, x-quad q), one_m-scaled
    float4 wr0 = *(const float4*)(w1 + (d * 4 + 0) * 16 + q * 4);
    float4 wr1 = *(const float4*)(w1 + (d * 4 + 1) * 16 + q * 4);
    float4 wr2 = *(const float4*)(w1 + (d * 4 + 2) * 16 + q * 4);
    float4 wr3 = *(const float4*)(w1 + (d * 4 + 3) * 16 + q * 4);
    wr0.x *= one_m; wr0.y *= one_m; wr0.z *= one_m; wr0.w *= one_m;
    wr1.x *= one_m; wr1.y *= one_m; wr1.z *= one_m; wr1.w *= one_m;
    wr2.x *= one_m; wr2.y *= one_m; wr2.z *= one_m; wr2.w *= one_m;
    wr3.x *= one_m; wr3.y *= one_m; wr3.z *= one_m; wr3.w *= one_m;

    // ---- zero out[b] (overlaps weight/x latency) --------------------------
    float4* o4 = (float4*)(out + (size_t)b * T_STEPS * 10);   // 10240 float4
    float4 z4 = make_float4(0.f, 0.f, 0.f, 0.f);
#pragma unroll
    for (int i = 0; i < 20; ++i) o4[i * 512 + tid] = z4;

    const float a2 = alpha * alpha;
    float aj = alpha;                       // alpha^(rl+1)
    if (rl & 1) aj *= alpha;
    if (rl & 2) aj *= a2;

    float* xw = xs + wv * 256;
    const int rdoff = rl * 16 + q * 4;
    const int gbase = wv * 2048;            // wave rows [wv*512, +512)
    const bool wlane = (rl == 3);

    float4 xa = xq4[gbase + ln];
    for (int g = 0; g < 32; ++g) {
        float4 xb;
        if (g < 31) xb = xq4[gbase + (g + 1) * 64 + ln];   // prefetch
        *(float4*)&xw[ln * 4] = xa;        // stage 16 rows (same-wave order)
#pragma unroll
        for (int p = 0; p < 4; ++p) {
            float4 xv = *(const float4*)&xw[p * 64 + rdoff];
            float p0 = fmaf(wr0.y, xv.y, wr0.x * xv.x);
            p0 = fmaf(wr0.z, xv.z, p0); p0 = fmaf(wr0.w, xv.w, p0);
            float p1 = fmaf(wr1.y, xv.y, wr1.x * xv.x);
            p1 = fmaf(wr1.z, xv.z, p1); p1 = fmaf(wr1.w, xv.w, p1);
            float p2 = fmaf(wr2.y, xv.y, wr2.x * xv.x);
            p2 = fmaf(wr2.z, xv.z, p2); p2 = fmaf(wr2.w, xv.w, p2);
            float p3 = fmaf(wr3.y, xv.y, wr3.x * xv.x);
            p3 = fmaf(wr3.z, xv.z, p3); p3 = fmaf(wr3.w, xv.w, p3);
            float s0 = qsum4(p0), s1 = qsum4(p1);
            float s2 = qsum4(p2), s3 = qsum4(p3);
            float y = (q == 0) ? s0 : (q == 1) ? s1 : (q == 2) ? s2 : s3;
            // 4-step alpha-prefix scan across rows (zero-fill = seg boundary)
            float z1 = fmaf(alpha, dppf<0x114>(y), y);
            float z2 = fmaf(a2,    dppf<0x118>(z1), z1);
            float u1 = fmaxf(z2, dppf<0x114>(z2));
            float u2 = fmaxf(u1, dppf<0x118>(u1));
            float t0 = z2 + aj;
            float t1 = fmaxf(t0, dppf<0x114>(t0));
            float t2 = fmaxf(t1, dppf<0x118>(t1));
            if (wlane) {
                const int seg = wv * 128 + g * 4 + p;
                endf[seg * EP + c] = z2;
                m01[seg * EP + c] =
                    (uint32_t)encq(u2) | ((uint32_t)encq(t2) << 16);
            }
        }
        xa = xb;
    }
    __syncthreads();   // all cert entries visible

    // ---- composition + certification: 16 ch x 8 eighths (128 lanes) -------
    if (tid < 128) {
        const int cc = tid & 15;
        const int e8 = tid >> 4;
        const int s0i = e8 * 128;
        float vs = 0.0f;
        if (e8 > 0) {   // 40-seg warm-up: alpha4^40 = e^-8 = 3.4e-4 carry err
#pragma unroll 8
            for (int s = s0i - 40; s < s0i; ++s)
                vs = fmaf(alpha4, vs, endf[s * EP + cc]);
        }
        uint32_t bw = 0;
        int bad = 0;
#pragma unroll 4
        for (int s = s0i; s < s0i + 128; ++s) {
            uint32_t mm = m01[s * EP + cc];
            float m0v = decq(mm & 0xffffu);
            float m1v = decq(mm >> 16);
            float vsu = fminf(fmaxf(vs + 1e-3f, 0.0f), 1.0f);
            float bound = fmaf(1.0f - vsu, m0v, vsu * m1v);
            if (!(bound < 0.999f)) { bw |= 1u << (s & 31); bad = 1; }
            if ((s & 31) == 31) { sh_badseg[cc][s >> 5] = bw; bw = 0; }
            vs = fmaf(alpha4, vs, endf[s * EP + cc]);
        }
        if (bad) atomicOr(&sh_badch, 1 << cc);
    }
    __syncthreads();

    // ---- parallel exact repair for cert-bad channels (rare) ---------------
    const int badmask = sh_badch;
    if (badmask) {
        uint4* sz = (uint4*)(s1t + (size_t)b * 16 * T_STEPS);
#pragma unroll
        for (int i = 0; i < 8; ++i) sz[i * 512 + tid] = make_uint4(0u,0u,0u,0u);
        __syncthreads();   // zeroing ordered before repair spike writes

        for (int rp = 0; rp < 2; ++rp) {
            const int idx = wv + rp * 8;
            int m = badmask;
            for (int i = 0; i < idx; ++i) m &= m - 1;
            if (ln == 0 && m) {
                const int cc = __ffs(m) - 1;
                float wc[16];
#pragma unroll
                for (int i = 0; i < 16; ++i) wc[i] = w1[cc * 16 + i];
                uint8_t* op = s1t + ((size_t)b * 16 + cc) * T_STEPS;
                float v = 0.0f;
                int any = 0;
                for (int w32 = 0; w32 < 32; ++w32) {
                    uint32_t bwv = sh_badseg[cc][w32];
                    const int sb = w32 * 32;
                    if (bwv == 0u) {
#pragma unroll 8
                        for (int qq = 0; qq < 32; ++qq)
                            v = fmaf(alpha4, v, endf[(sb + qq) * EP + cc]);
                    } else {
                        for (int qq = 0; qq < 32; ++qq) {
                            const int s = sb + qq;
                            if (!((bwv >> qq) & 1u)) {
                                v = fmaf(alpha4, v, endf[s * EP + cc]);
                                continue;
                            }
                            const float4* xr2 = xq4 + (size_t)s * 16;
                            uint32_t sw = 0u;
#pragma unroll
                            for (int j = 0; j < 4; ++j) {
                                float y = dot16(wc, xr2[j*4+0], xr2[j*4+1],
                                                     xr2[j*4+2], xr2[j*4+3]);
                                float sp = lif_step(v, one_m * y, alpha);
                                sw |= ((uint32_t)(int)sp) << (j * 8);
                            }
                            if (sw) {
                                *(uint32_t*)(op + s * 4) = sw;
                                sh_bm1[s >> 2] = 1;
                                any = 1;
                            }
                        }
                    }
                }
                if (any) sh_spike = 1;
            }
        }
    }
    __syncthreads();   // orders repair writes + sh_spike/sh_bm1 for readers

    // ---- fused layer-2: sparse scan s1t -> s2t (+ sh_bm2) -----------------
    if (sh_spike) {
        if (tid < 32) {
            const int c2 = tid;
            float wv2[16];
#pragma unroll
            for (int i = 0; i < 16; ++i) wv2[i] = one_m * w2[c2 * 16 + i];
            const uint8_t* sb1 = s1t + (size_t)b * 16 * T_STEPS;
            uint4* op2 = (uint4*)(s2t + ((size_t)b * 32 + c2) * T_STEPS);
            const uint4* bmv = (const uint4*)sh_bm1;
            float v = 0.0f;
            for (int sb = 0; sb < 16; ++sb) {
                uint4 bm = bmv[sb];
                if ((bm.x | bm.y | bm.z | bm.w) == 0u) {
                    if (v != 0.0f) {
                        for (int blk = 0; blk < 16 && v != 0.0f; ++blk) {
#pragma unroll
                            for (int j = 0; j < 16; ++j) v *= alpha;
                        }
                    }
                    continue;
                }
                for (int blk = 0; blk < 16; ++blk) {
                    uint32_t dd = (blk < 4) ? bm.x : (blk < 8) ? bm.y
                                : (blk < 12) ? bm.z : bm.w;
                    uint32_t byte = (dd >> ((blk & 3) * 8)) & 0xffu;
                    if (byte == 0u) {
                        if (v != 0.0f) {
#pragma unroll
                            for (int j = 0; j < 16; ++j) v *= alpha;
                        }
                        continue;
                    }
                    const int tb = sb * 16 + blk;
                    const int t0 = tb * 16;
                    uint4 S[16];
#pragma unroll
                    for (int cx = 0; cx < 16; ++cx)
                        S[cx] = *(const uint4*)(sb1 + (size_t)cx * T_STEPS + t0);
                    uint32_t w[4] = {0u, 0u, 0u, 0u};
#pragma unroll
                    for (int j = 0; j < 16; ++j) {
                        float xv[16];
#pragma unroll
                        for (int cx = 0; cx < 16; ++cx) {
                            uint32_t d2 = (j < 4) ? S[cx].x : (j < 8) ? S[cx].y
                                        : (j < 12) ? S[cx].z : S[cx].w;
                            xv[cx] = ubf(d2, j & 3);
                        }
                        float p0 = fmaf(wv2[1], xv[1], wv2[0] * xv[0]);
                        p0 = fmaf(wv2[2], xv[2], p0);   p0 = fmaf(wv2[3], xv[3], p0);
                        float p1 = fmaf(wv2[5], xv[5], wv2[4] * xv[4]);
                        p1 = fmaf(wv2[6], xv[6], p1);   p1 = fmaf(wv2[7], xv[7], p1);
                        float p2 = fmaf(wv2[9], xv[9], wv2[8] * xv[8]);
                        p2 = fmaf(wv2[10], xv[10], p2); p2 = fmaf(wv2[11], xv[11], p2);
                        float p3 = fmaf(wv2[13], xv[13], wv2[12] * xv[12]);
                        p3 = fmaf(wv2[14], xv[14], p3); p3 = fmaf(wv2[15], xv[15], p3);
                        float xsv = (p0 + p1) + (p2 + p3);
                        float s = lif_step(v, xsv, alpha);
                        w[j >> 2] |= ((uint32_t)(int)s) << ((j & 3) * 8);
                    }
                    op2[tb] = make_uint4(w[0], w[1], w[2], w[3]);
                    if (w[0] | w[1] | w[2] | w[3]) { sh_bm2[tb] = 1; sh_flag2 = 1; }
                }
            }
        }
        __syncthreads();   // s2t/sh_bm2/sh_flag2 visible

        // ---- fused layer-3: sparse scan s2t -> out (pre-zeroed) -----------
        if (sh_flag2 && tid < 16) {
            const int c3 = tid;
            const bool active = (c3 < 10);
            float wv3[32];
#pragma unroll
            for (int i = 0; i < 32; ++i)
                wv3[i] = active ? (one_m * w3[c3 * 32 + i]) : 0.0f;
            const uint8_t* sb2 = s2t + (size_t)b * 32 * T_STEPS;
            const uint4* bmv2 = (const uint4*)sh_bm2;
            float* ob = out + (size_t)b * T_STEPS * 10 + c3;
            float v = 0.0f;
            for (int sb = 0; sb < 16; ++sb) {
                uint4 bm = bmv2[sb];
                if ((bm.x | bm.y | bm.z | bm.w) == 0u) {
                    if (v != 0.0f) {
                        for (int blk = 0; blk < 16 && v != 0.0f; ++blk) {
#pragma unroll
                            for (int j = 0; j < 16; ++j) v *= alpha;
                        }
                    }
                    continue;
                }
                for (int blk = 0; blk < 16; ++blk) {
                    uint32_t dd = (blk < 4) ? bm.x : (blk < 8) ? bm.y
                                : (blk < 12) ? bm.z : bm.w;
                    uint32_t byte = (dd >> ((blk & 3) * 8)) & 0xffu;
                    if (byte == 0u) {
                        if (v != 0.0f) {
#pragma unroll
                            for (int j = 0; j < 16; ++j) v *= alpha;
                        }
                        continue;
                    }
                    const int t0 = (sb * 16 + blk) * 16;
                    uint4 S[32];
#pragma unroll
                    for (int cx = 0; cx < 32; ++cx)
                        S[cx] = *(const uint4*)(sb2 + (size_t)cx * T_STEPS + t0);
#pragma unroll
                    for (int j = 0; j < 16; ++j) {
                        float xv[32];
#pragma unroll
                        for (int cx = 0; cx < 32; ++cx) {
                            uint32_t d2 = (j < 4) ? S[cx].x : (j < 8) ? S[cx].y
                                        : (j < 12) ? S[cx].z : S[cx].w;
                            xv[cx] = ubf(d2, j & 3);
                        }
                        float p0 = fmaf(wv3[1], xv[1], wv3[0] * xv[0]);
                        p0 = fmaf(wv3[2],  xv[2],  p0); p0 = fmaf(wv3[3],  xv[3],  p0);
                        p0 = fmaf(wv3[4],  xv[4],  p0); p0 = fmaf(wv3[5],  xv[5],  p0);
                        p0 = fmaf(wv3[6],  xv[6],  p0); p0 = fmaf(wv3[7],  xv[7],  p0);
                        float p1 = fmaf(wv3[9], xv[9], wv3[8] * xv[8]);
                        p1 = fmaf(wv3[10], xv[10], p1); p1 = fmaf(wv3[11], xv[11], p1);
                        p1 = fmaf(wv3[12], xv[12], p1); p1 = fmaf(wv3[13], xv[13], p1);
                        p1 = fmaf(wv3[14], xv[14], p1); p1 = fmaf(wv3[15], xv[15], p1);
                        float p2 = fmaf(wv3[17], xv[17], wv3[16] * xv[16]);
                        p2 = fmaf(wv3[18], xv[18], p2); p2 = fmaf(wv3[19], xv[19], p2);
                        p2 = fmaf(wv3[20], xv[20], p2); p2 = fmaf(wv3[21], xv[21], p2);
                        p2 = fmaf(wv3[22], xv[22], p2); p2 = fmaf(wv3[23], xv[23], p2);
                        float p3 = fmaf(wv3[25], xv[25], wv3[24] * xv[24]);
                        p3 = fmaf(wv3[26], xv[26], p3); p3 = fmaf(wv3[27], xv[27], p3);
                        p3 = fmaf(wv3[28], xv[28], p3); p3 = fmaf(wv3[29], xv[29], p3);
                        p3 = fmaf(wv3[30], xv[30], p3); p3 = fmaf(wv3[31], xv[31], p3);
                        float xsv = (p0 + p1) + (p2 + p3);
                        float s = lif_step(v, xsv, alpha);
                        if (active && s != 0.0f) ob[(size_t)(t0 + j) * 10] = s;
                    }
                }
            }
        }
    }
}

extern "C" void kernel_launch(void* const* d_in, const int* in_sizes, int n_in,
                              void* d_out, int out_size, void* d_ws, size_t ws_size,
                              hipStream_t stream)
{
    const float* data = (const float*)d_in[0];
    const float* w1   = (const float*)d_in[1];
    const float* w2   = (const float*)d_in[2];
    const float* w3   = (const float*)d_in[3];
    float* out = (float*)d_out;

    // ws layout (48 MiB):
    //   [0, 16M)    s1t  u8 [256][16][4096] (dense-zeroed only for bad b)
    //   [16M, 48M)  s2t  u8 [256][32][4096] (sparse: only bm2-set blocks)
    uint8_t* ws  = (uint8_t*)d_ws;
    uint8_t* s1t = ws;
    uint8_t* s2t = ws + (16u << 20);

    const float alpha  = expf(-1.0f / 20.0f);
    const float one_m  = 1.0f - alpha;
    const float alpha4 = expf(-4.0f / 20.0f);

    fused<<<BATCH, 512, 0, stream>>>(data, w1, w2, w3, out, s1t, s2t,
                                     alpha, one_m, alpha4);
}